// Round 1
// baseline (2131.096 us; speedup 1.0000x reference)
//
#include <hip/hip_runtime.h>
#include <math.h>

// SplineCNN on MI355X.
// Strategy: counting-sort edges by dst each call; per 16-node tile, accumulate
// basis-weighted x[src] into LDS acc[t][26][Cin] (slot 25 = self features for the
// root term), then transform with W k-slices staged through LDS. No atomics in
// the hot path: one wave owns one node's edge list; lanes = input channels,
// combos split across lanes (the 4 kernel indices of an edge are distinct).

constexpr int BLK = 512;

// ---------------------------------------------------------------- preprocessing

__global__ void hist_kernel(const int* __restrict__ ei, int* __restrict__ deg, int E) {
    int e = blockIdx.x * blockDim.x + threadIdx.x;
    if (e < E) atomicAdd(&deg[ei[E + e]], 1);
}

__global__ __launch_bounds__(256) void scan_kernel(const int* __restrict__ deg,
                                                   int* __restrict__ row_start,
                                                   int* __restrict__ cursor,
                                                   float* __restrict__ invdeg, int n) {
    __shared__ int wsum[4];
    int tid = threadIdx.x, lane = tid & 63, wave = tid >> 6;
    int carry = 0;
    for (int base = 0; base < n; base += 2048) {
        int idx0 = base + tid * 8;
        int v[8], pre[8];
        int s = 0;
        #pragma unroll
        for (int u = 0; u < 8; ++u) {
            int id = idx0 + u;
            v[u] = (id < n) ? deg[id] : 0;
            pre[u] = s;
            s += v[u];
        }
        int inc = s;
        #pragma unroll
        for (int off = 1; off < 64; off <<= 1) {
            int t = __shfl_up(inc, off);
            if (lane >= off) inc += t;
        }
        if (lane == 63) wsum[wave] = inc;
        __syncthreads();
        int woff = 0;
        for (int w2 = 0; w2 < wave; ++w2) woff += wsum[w2];
        int tot = wsum[0] + wsum[1] + wsum[2] + wsum[3];
        int eb = carry + woff + inc - s;
        #pragma unroll
        for (int u = 0; u < 8; ++u) {
            int id = idx0 + u;
            if (id < n) {
                int rs = eb + pre[u];
                row_start[id] = rs;
                cursor[id] = rs;
                invdeg[id] = 1.0f / fmaxf((float)v[u], 1.0f);
            }
        }
        carry += tot;
        __syncthreads();
    }
    if (tid == 0) row_start[n] = carry;
}

// Edge record: 32B = float4 basis (pre-scaled by 1/deg[dst]) + {src, idxpack, dst, 0}
__global__ void scatter_kernel(const int* __restrict__ ei, const float* __restrict__ pseudo,
                               const float* __restrict__ invdeg, int* __restrict__ cursor,
                               float4* __restrict__ edges, int E) {
    int e = blockIdx.x * blockDim.x + threadIdx.x;
    if (e >= E) return;
    int src = ei[e], dst = ei[E + e];
    float p0 = pseudo[2 * e], p1 = pseudo[2 * e + 1];
    float v0 = fminf(fmaxf(p0, 0.f), 1.f) * 4.f;
    float v1 = fminf(fmaxf(p1, 0.f), 1.f) * 4.f;
    int k00 = min((int)floorf(v0), 3);
    int k01 = min((int)floorf(v1), 3);
    float f0 = v0 - (float)k00, f1 = v1 - (float)k01;
    float g0 = 1.f - f0, g1 = 1.f - f1;
    float sc = invdeg[dst];
    float4 b;
    b.x = g0 * g1 * sc;  // combo (0,0)
    b.y = g0 * f1 * sc;  // combo (0,1)
    b.z = f0 * g1 * sc;  // combo (1,0)
    b.w = f0 * f1 * sc;  // combo (1,1)
    int i00 = k00 * 5 + k01;
    unsigned ip = (unsigned)i00 | ((unsigned)(i00 + 1) << 8) |
                  ((unsigned)(i00 + 5) << 16) | ((unsigned)(i00 + 6) << 24);
    int pos = atomicAdd(&cursor[dst], 1);
    edges[pos * 2] = b;
    float4 m;
    m.x = __int_as_float(src);
    m.y = __uint_as_float((int)ip);
    m.z = __int_as_float(dst);
    m.w = 0.f;
    edges[pos * 2 + 1] = m;
}

// ---------------------------------------------------------------- fused layer

template <int Cin, int Cout, int T, int BLOCK>
__global__ __launch_bounds__(BLOCK) void layer_kernel(
        const float* __restrict__ xin, const float* __restrict__ W,
        const float* __restrict__ root, const float* __restrict__ bias,
        const int* __restrict__ row_start, const float4* __restrict__ edges,
        float* __restrict__ xout, int nNodes) {
    __shared__ __align__(16) float acc[T][26][Cin];
    __shared__ __align__(16) float wt[Cin][Cout];
    const int tid = threadIdx.x;
    const int node0 = blockIdx.x * T;

    // init: zero k<25, load self features into slot 25
    for (int p = tid; p < T * 26 * Cin; p += BLOCK) {
        int t = p / (26 * Cin);
        int r = p - t * (26 * Cin);
        int k = r / Cin;
        int i = r - k * Cin;
        float v = 0.f;
        int n = node0 + t;
        if (k == 25 && n < nNodes) v = xin[n * Cin + i];
        (&acc[0][0][0])[p] = v;
    }
    __syncthreads();

    // phase A: edge accumulation (one wave per node, lanes = channels x combos)
    const int wave = tid >> 6, lane = tid & 63;
    constexpr int NW = BLOCK / 64;
    int ch;
    bool act;
    if constexpr (Cin == 64) { ch = lane; act = true; }
    else if constexpr (Cin == 32) { ch = lane & 31; act = true; }
    else { ch = lane & 7; act = (lane < 32); }

    for (int t = wave; t < T; t += NW) {
        int n = node0 + t;
        if (n >= nNodes) break;
        int eb = row_start[n], ee = row_start[n + 1];
        float* accN = &acc[t][0][0];
        for (int e = eb; e < ee; e += 4) {
            float4 bb[4];
            int srcs[4];
            unsigned ips[4];
            float valm[4];
            #pragma unroll
            for (int u = 0; u < 4; ++u) {
                int e2 = (e + u < ee) ? (e + u) : (ee - 1);
                float4 bs = edges[e2 * 2];
                float4 mm = edges[e2 * 2 + 1];
                bb[u] = bs;
                srcs[u] = __float_as_int(mm.x);
                ips[u] = (unsigned)__float_as_int(mm.y);
                valm[u] = (e + u < ee) ? 1.f : 0.f;
            }
            float xv[4];
            #pragma unroll
            for (int u = 0; u < 4; ++u)
                xv[u] = act ? xin[srcs[u] * Cin + ch] * valm[u] : 0.f;
            #pragma unroll
            for (int u = 0; u < 4; ++u) {
                if (!act) continue;
                unsigned ip = ips[u];
                if constexpr (Cin == 64) {
                    accN[((ip) & 255) * Cin + ch]       += bb[u].x * xv[u];
                    accN[((ip >> 8) & 255) * Cin + ch]  += bb[u].y * xv[u];
                    accN[((ip >> 16) & 255) * Cin + ch] += bb[u].z * xv[u];
                    accN[((ip >> 24) & 255) * Cin + ch] += bb[u].w * xv[u];
                } else if constexpr (Cin == 32) {
                    bool lo = (lane < 32);
                    unsigned shA = lo ? 0u : 16u, shB = lo ? 8u : 24u;
                    float bA = lo ? bb[u].x : bb[u].z;
                    float bB = lo ? bb[u].y : bb[u].w;
                    int iA = (ip >> shA) & 255;
                    int iB = (ip >> shB) & 255;
                    accN[iA * Cin + ch] += bA * xv[u];
                    accN[iB * Cin + ch] += bB * xv[u];
                } else {
                    int c = (lane >> 3) & 3;
                    float bs = (c == 0) ? bb[u].x : (c == 1) ? bb[u].y : (c == 2) ? bb[u].z : bb[u].w;
                    int idx = (ip >> (8 * c)) & 255;
                    accN[idx * Cin + ch] += bs * xv[u];
                }
            }
        }
    }
    __syncthreads();

    // phase B: out[t][o] = sum_k acc[t][k][:] . wt[:][o]  (k=25 -> root), +bias, elu
    constexpr int TG = BLOCK / Cout;
    constexpr int TPT = T / TG;
    static_assert(TG * TPT == T, "tile mapping");
    const int o = tid % Cout;
    const int tg = tid / Cout;
    float out[TPT];
    #pragma unroll
    for (int tt = 0; tt < TPT; ++tt) out[tt] = bias[o];

    for (int k = 0; k < 26; ++k) {
        const float* wsrc = (k < 25) ? (W + k * Cin * Cout) : root;
        __syncthreads();
        for (int p = tid; p < Cin * Cout; p += BLOCK) (&wt[0][0])[p] = wsrc[p];
        __syncthreads();
        #pragma unroll
        for (int ii = 0; ii < Cin; ii += 4) {
            float w0 = wt[ii][o], w1 = wt[ii + 1][o], w2 = wt[ii + 2][o], w3 = wt[ii + 3][o];
            #pragma unroll
            for (int tt = 0; tt < TPT; ++tt) {
                const float4 a4 = *(const float4*)&acc[tg * TPT + tt][k][ii];
                out[tt] += a4.x * w0 + a4.y * w1 + a4.z * w2 + a4.w * w3;
            }
        }
    }
    #pragma unroll
    for (int tt = 0; tt < TPT; ++tt) {
        int n = node0 + tg * TPT + tt;
        if (n < nNodes) {
            float v = out[tt];
            v = (v > 0.f) ? v : expm1f(v);
            xout[n * Cout + o] = v;
        }
    }
}

// ---------------------------------------------------------------- pooling + head

__global__ void pool_kernel(const float* __restrict__ h, const int* __restrict__ batch,
                            float* __restrict__ pooled, float* __restrict__ cnt, int n) {
    int gw = (blockIdx.x * blockDim.x + threadIdx.x) >> 6;
    int lane = threadIdx.x & 63;
    int nw = (gridDim.x * blockDim.x) >> 6;
    int per = (n + nw - 1) / nw;
    int n0 = gw * per, n1 = min(n0 + per, n);
    if (n0 >= n1) return;
    int cur = batch[n0];
    float s = 0.f, c = 0.f;
    for (int nn = n0; nn < n1; ++nn) {
        int g = batch[nn];
        if (g != cur) {
            atomicAdd(&pooled[cur * 64 + lane], s);
            if (lane == 0) atomicAdd(&cnt[cur], c);
            s = 0.f; c = 0.f; cur = g;
        }
        s += h[nn * 64 + lane];
        c += 1.f;
    }
    atomicAdd(&pooled[cur * 64 + lane], s);
    if (lane == 0) atomicAdd(&cnt[cur], c);
}

__global__ __launch_bounds__(128) void head_kernel(const float* __restrict__ pooled,
                                                   const float* __restrict__ cnt,
                                                   const float* __restrict__ fcw,
                                                   const float* __restrict__ fcb,
                                                   float* __restrict__ outp, int G) {
    int g = threadIdx.x;
    if (g >= G) return;
    float inv = 1.f / fmaxf(cnt[g], 1.f);
    float l[30];
    float m = -1e30f;
    #pragma unroll
    for (int j = 0; j < 30; ++j) {
        float s = fcb[j];
        for (int i = 0; i < 64; ++i) s += pooled[g * 64 + i] * inv * fcw[i * 30 + j];
        l[j] = s;
        m = fmaxf(m, s);
    }
    float lse = 0.f;
    #pragma unroll
    for (int j = 0; j < 30; ++j) lse += expf(l[j] - m);
    lse = logf(lse);
    #pragma unroll
    for (int j = 0; j < 30; ++j) outp[g * 30 + j] = l[j] - m - lse;
}

// ---------------------------------------------------------------- launch

template <int Cin, int Cout, int T>
static void launch_layer(const float* xin, const float* W, const float* root, const float* bias,
                         const int* row_start, const float4* edges, float* xout, int nN,
                         hipStream_t s) {
    int nb = (nN + T - 1) / T;
    layer_kernel<Cin, Cout, T, BLK><<<nb, BLK, 0, s>>>(xin, W, root, bias, row_start, edges, xout, nN);
}

extern "C" void kernel_launch(void* const* d_in, const int* in_sizes, int n_in,
                              void* d_out, int out_size, void* d_ws, size_t ws_size,
                              hipStream_t stream) {
    const float* x = (const float*)d_in[0];
    const int* ei = (const int*)d_in[1];
    const float* ps = (const float*)d_in[2];
    const int* batch = (const int*)d_in[3];
    const float *w1 = (const float*)d_in[4], *r1 = (const float*)d_in[5], *b1 = (const float*)d_in[6];
    const float *w2 = (const float*)d_in[7], *r2 = (const float*)d_in[8], *b2 = (const float*)d_in[9];
    const float *w3 = (const float*)d_in[10], *r3 = (const float*)d_in[11], *b3 = (const float*)d_in[12];
    const float *fcw = (const float*)d_in[13], *fcb = (const float*)d_in[14];
    float* outp = (float*)d_out;

    const int nN = in_sizes[0] / 8;  // 50000
    const int E = in_sizes[1] / 2;   // 800000
    const int G = out_size / 30;     // 128

    char* wsb = (char*)d_ws;
    size_t off = 0;
    auto alloc = [&](size_t b) -> char* {
        char* p = wsb + off;
        off = (off + b + 255) & ~(size_t)255;
        return p;
    };
    int* deg = (int*)alloc((size_t)nN * 4);
    int* row_start = (int*)alloc((size_t)(nN + 1) * 4);
    int* cursor = (int*)alloc((size_t)nN * 4);
    float* invdeg = (float*)alloc((size_t)nN * 4);
    float4* edges = (float4*)alloc((size_t)E * 32);
    float* h1 = (float*)alloc((size_t)nN * 32 * 4);
    float* h2 = (float*)alloc((size_t)nN * 64 * 4);
    float* h3 = (float*)alloc((size_t)nN * 64 * 4);
    float* pooled = (float*)alloc((size_t)G * 64 * 4);
    float* cnt = (float*)alloc((size_t)G * 4);
    (void)ws_size;

    hipMemsetAsync(deg, 0, (size_t)nN * 4, stream);
    hipMemsetAsync(pooled, 0, (size_t)G * 64 * 4, stream);
    hipMemsetAsync(cnt, 0, (size_t)G * 4, stream);

    int ebk = (E + 255) / 256;
    hist_kernel<<<ebk, 256, 0, stream>>>(ei, deg, E);
    scan_kernel<<<1, 256, 0, stream>>>(deg, row_start, cursor, invdeg, nN);
    scatter_kernel<<<ebk, 256, 0, stream>>>(ei, ps, invdeg, cursor, edges, E);

    launch_layer<8, 32, 16>(x, w1, r1, b1, row_start, edges, h1, nN, stream);
    launch_layer<32, 64, 16>(h1, w2, r2, b2, row_start, edges, h2, nN, stream);
    launch_layer<64, 64, 16>(h2, w3, r3, b3, row_start, edges, h3, nN, stream);

    pool_kernel<<<128, 256, 0, stream>>>(h3, batch, pooled, cnt, nN);
    head_kernel<<<1, 128, 0, stream>>>(pooled, cnt, fcw, fcb, outp, G);
}